// Round 2
// baseline (218.683 us; speedup 1.0000x reference)
//
#include <hip/hip_runtime.h>
#include <math.h>
#include <stdint.h>

#define NTOT   8192
#define HALF_N 4096
#define DIM    512
#define INV_T  14.2857142857142857f   // 1/0.07
#define NTILE  32                     // 8192 / 256
#define NBLK   528                    // 32*33/2, triangular; 528 % 8 == 0 -> bijective XCD swizzle

using s16x8 = __attribute__((ext_vector_type(8))) short;
using f32x4 = __attribute__((ext_vector_type(4))) float;

// Scratch in static device globals (fully rewritten every call; no d_ws use).
__device__ unsigned short g_fnb[NTOT * DIM];   // normalized bf16 matrix, 8 MB
__device__ float g_pos[NTOT];
__device__ float g_sumexp[NTOT];
__device__ int   g_cnt[NTOT];

__device__ __forceinline__ float bf2f(unsigned short u) {
  union { unsigned int i; float f; } v; v.i = ((unsigned int)u) << 16; return v.f;
}
__device__ __forceinline__ unsigned short f2bf(float x) {
  union { float f; unsigned int i; } v; v.f = x;
  unsigned int u = v.i;
  return (unsigned short)((u + 0x7FFFu + ((u >> 16) & 1u)) >> 16);
}

// async global->LDS, 16 B per lane. LDS dest is wave-uniform base + lane*16.
__device__ __forceinline__ void gload16(const unsigned short* g, unsigned short* l) {
  __builtin_amdgcn_global_load_lds(
      (const __attribute__((address_space(1))) unsigned int*)g,
      (__attribute__((address_space(3))) unsigned int*)l, 16, 0, 0);
}

// ---------------- kernel 1: normalize pairs -> bf16, pos, zero stats ----------------
__global__ __launch_bounds__(256) void knorm(const float* __restrict__ f1,
                                             const float* __restrict__ f2) {
  const int tid  = threadIdx.x;
  const int wv   = tid >> 6;
  const int pi   = wv >> 1;            // pair within block
  const int half = wv & 1;             // 0: f1 row, 1: f2 row
  const int lane = tid & 63;
  const int b    = blockIdx.x * 2 + pi;
  const int row  = b + half * HALF_N;

  if (tid < 4) {                       // zero the 4 stat rows this block owns
    const int r = blockIdx.x * 2 + (tid & 1) + (tid >> 1) * HALF_N;
    g_sumexp[r] = 0.f; g_cnt[r] = 0;
  }

  const float* src = (half == 0) ? (f1 + (size_t)b * DIM) : (f2 + (size_t)b * DIM);
  float4 v0 = ((const float4*)src)[lane];
  float4 v1 = ((const float4*)src)[lane + 64];
  float ss = v0.x*v0.x + v0.y*v0.y + v0.z*v0.z + v0.w*v0.w
           + v1.x*v1.x + v1.y*v1.y + v1.z*v1.z + v1.w*v1.w;
  #pragma unroll
  for (int o = 32; o >= 1; o >>= 1) ss += __shfl_xor(ss, o, 64);
  const float sc = 1.0f / fmaxf(sqrtf(ss), 1e-8f);
  ushort4 h0, h1;
  h0.x = f2bf(v0.x * sc); h0.y = f2bf(v0.y * sc);
  h0.z = f2bf(v0.z * sc); h0.w = f2bf(v0.w * sc);
  h1.x = f2bf(v1.x * sc); h1.y = f2bf(v1.y * sc);
  h1.z = f2bf(v1.z * sc); h1.w = f2bf(v1.w * sc);
  ushort4* dst = (ushort4*)(g_fnb + (size_t)row * DIM);
  dst[lane]      = h0;
  dst[lane + 64] = h1;

  // pos[b] = <fn_b, fn_{b+4096}> on the same bf16 values the GEMM uses
  __shared__ ushort4 sh[2][64][2];
  if (half == 1) { sh[pi][lane][0] = h0; sh[pi][lane][1] = h1; }
  __syncthreads();
  if (half == 0) {
    const ushort4 p0 = sh[pi][lane][0], p1 = sh[pi][lane][1];
    float s = bf2f(h0.x)*bf2f(p0.x) + bf2f(h0.y)*bf2f(p0.y)
            + bf2f(h0.z)*bf2f(p0.z) + bf2f(h0.w)*bf2f(p0.w)
            + bf2f(h1.x)*bf2f(p1.x) + bf2f(h1.y)*bf2f(p1.y)
            + bf2f(h1.z)*bf2f(p1.z) + bf2f(h1.w)*bf2f(p1.w);
    #pragma unroll
    for (int o = 32; o >= 1; o >>= 1) s += __shfl_xor(s, o, 64);
    if (lane == 0) { g_pos[b] = s; g_pos[b + HALF_N] = s; }
  }
}

// ---------------- kernel 2: 256x256-tile symmetric fused GEMM + reductions ----------------
// R2: 256^2 tile (528 triangular blocks, 4x fewer epilogues/atomics, halved
// logical staging traffic), 512 threads / 8 waves (2Mx4N), LDS double-buffer
// 128 KB, 2-phase pipeline with COUNTED vmcnt (stage kt+1 flies across the
// barrier while kt computes; never vmcnt(0) mid-loop), raw s_barrier +
// rule-18 sched_barrier fences, bijective XCD swizzle (528 = 8*66).
// Swizzle discipline: linear gload_lds dest + inverse-swizzled global source
// + swizzled ds_read (same XOR involution). __launch_bounds__(512,2): VGPR
// cap 256 (acc 128 + frags 48 + addr ~30), 1 block/CU.
__global__ __launch_bounds__(512, 2) void kmain() {
  __shared__ __align__(16) unsigned short As[2][256 * 64];
  __shared__ __align__(16) unsigned short Bs[2][256 * 64];

  // bijective XCD swizzle then triangular decode: t -> (bi, bj), bi <= bj
  int t = (blockIdx.x & 7) * (NBLK / 8) + (blockIdx.x >> 3);
  int bi = 0, rem = NTILE;
  while (t >= rem) { t -= rem; --rem; ++bi; }
  const int bj = bi + t;
  const bool offdiag = (bi != bj);
  const int i0 = bi * 256, j0 = bj * 256;

  const int tid  = threadIdx.x;
  const int lane = tid & 63;
  const int w    = tid >> 6;        // 0..7
  const int wm   = w >> 2;          // 0..1 : row group, 128 rows
  const int wn   = w & 3;           // 0..3 : col group, 64 cols
  const int lrow = lane & 15;
  const int lq   = lane >> 4;

  // staging: wave w covers tile rows [w*32, w*32+32) in 4 chunks of 8 rows.
  // Lane l -> LDS bytes chunk_base + l*16: row = 8q + (l>>3), physical col
  // block p = l&7 which must hold logical block p ^ (row&7).
  const int rsub = lane >> 3;
  const int lcb  = (lane & 7) ^ rsub;
  const unsigned short* Ag = g_fnb + (size_t)(i0 + w * 32 + rsub) * DIM + lcb * 8;
  const unsigned short* Bg = g_fnb + (size_t)(j0 + w * 32 + rsub) * DIM + lcb * 8;

  f32x4 acc[8][4];
  #pragma unroll
  for (int a = 0; a < 8; ++a)
    #pragma unroll
    for (int bb = 0; bb < 4; ++bb) { acc[a][bb][0]=0.f; acc[a][bb][1]=0.f; acc[a][bb][2]=0.f; acc[a][bb][3]=0.f; }

  auto stage = [&](int kb, int buf) {
    unsigned short* ad = &As[buf][(w * 32) * 64];
    #pragma unroll
    for (int q = 0; q < 4; ++q)
      gload16(Ag + (size_t)(q * 8) * DIM + kb, ad + q * 512);
    if (offdiag) {
      unsigned short* bd = &Bs[buf][(w * 32) * 64];
      #pragma unroll
      for (int q = 0; q < 4; ++q)
        gload16(Bg + (size_t)(q * 8) * DIM + kb, bd + q * 512);
    }
  };

  stage(0, 0);                             // prologue: tile 0 in flight

  for (int kt = 0; kt < 8; ++kt) {
    const int cur = kt & 1;
    if (kt < 7) stage((kt + 1) * 64, cur ^ 1);   // next tile flies during compute
    // wait for CURRENT tile only: next tile's loads stay outstanding
    if (kt < 7) {
      if (offdiag) asm volatile("s_waitcnt vmcnt(8)" ::: "memory");
      else         asm volatile("s_waitcnt vmcnt(4)" ::: "memory");
    } else {
      asm volatile("s_waitcnt vmcnt(0)" ::: "memory");
    }
    __builtin_amdgcn_sched_barrier(0);
    __builtin_amdgcn_s_barrier();          // all waves' current-tile loads landed
    __builtin_amdgcn_sched_barrier(0);

    const unsigned short* Acur = &As[cur][0];
    const unsigned short* Bcur = offdiag ? &Bs[cur][0] : &As[cur][0];
    #pragma unroll
    for (int kk = 0; kk < 2; ++kk) {
      s16x8 af[8], bf[4];
      #pragma unroll
      for (int mi = 0; mi < 8; ++mi) {
        const int r = wm * 128 + mi * 16 + lrow;
        af[mi] = *(const s16x8*)(&Acur[r * 64 + (((kk * 4 + lq) ^ (lrow & 7)) * 8)]);
      }
      #pragma unroll
      for (int ni = 0; ni < 4; ++ni) {
        const int r = wn * 64 + ni * 16 + lrow;
        bf[ni] = *(const s16x8*)(&Bcur[r * 64 + (((kk * 4 + lq) ^ (lrow & 7)) * 8)]);
      }
      #pragma unroll
      for (int mi = 0; mi < 8; ++mi)
        #pragma unroll
        for (int ni = 0; ni < 4; ++ni)
          acc[mi][ni] = __builtin_amdgcn_mfma_f32_16x16x32_bf16(af[mi], bf[ni], acc[mi][ni], 0, 0, 0);
    }
    asm volatile("s_waitcnt lgkmcnt(0)" ::: "memory");   // buf[cur] reads retired
    __builtin_amdgcn_sched_barrier(0);
    __builtin_amdgcn_s_barrier();          // safe to overwrite buf[cur] next iter
  }

  // ---- epilogue. C layout: col = lrow (+ni*16+wn*64), row = lq*4+r (+mi*16+wm*128).
  // row side (always)
  #pragma unroll
  for (int mi = 0; mi < 8; ++mi) {
    #pragma unroll
    for (int r = 0; r < 4; ++r) {
      const int i  = i0 + wm * 128 + mi * 16 + lq * 4 + r;
      const float pv = g_pos[i];
      float s = 0.f; int c = 0;
      #pragma unroll
      for (int ni = 0; ni < 4; ++ni) {
        const int j = j0 + wn * 64 + ni * 16 + lrow;
        const float v = acc[mi][ni][r];
        const float e = __expf(v * INV_T);
        const bool diag = (j == i);
        s += diag ? 0.f : e;
        c += (!diag && (j != (i ^ HALF_N)) && (v > pv)) ? 1 : 0;
      }
      #pragma unroll
      for (int o = 1; o < 16; o <<= 1) {
        s += __shfl_xor(s, o, 64);
        c += __shfl_xor(c, o, 64);
      }
      if (lrow == 0) {
        atomicAdd(&g_sumexp[i], s);
        atomicAdd(&g_cnt[i], c);
      }
    }
  }

  // col side (off-diagonal only; i and j slabs disjoint -> j != i always)
  if (offdiag) {
    #pragma unroll
    for (int ni = 0; ni < 4; ++ni) {
      const int j  = j0 + wn * 64 + ni * 16 + lrow;
      const float pj = g_pos[j];
      float s = 0.f; int c = 0;
      #pragma unroll
      for (int mi = 0; mi < 8; ++mi) {
        #pragma unroll
        for (int r = 0; r < 4; ++r) {
          const int i = i0 + wm * 128 + mi * 16 + lq * 4 + r;
          const float v = acc[mi][ni][r];
          s += __expf(v * INV_T);
          c += ((i != (j ^ HALF_N)) && (v > pj)) ? 1 : 0;
        }
      }
      s += __shfl_xor(s, 16, 64); s += __shfl_xor(s, 32, 64);
      c += __shfl_xor(c, 16, 64); c += __shfl_xor(c, 32, 64);
      if (lq == 0) {
        atomicAdd(&g_sumexp[j], s);
        atomicAdd(&g_cnt[j], c);
      }
    }
  }
}

// ---------------- kernel 3: finalize the 4 scalars ----------------
__global__ __launch_bounds__(1024) void kfin(float* __restrict__ out) {
  const int tid = threadIdx.x;
  float nll = 0.f, t1 = 0.f, t5 = 0.f, mr = 0.f;
  for (int i = tid; i < NTOT; i += 1024) {
    nll += -g_pos[i] * INV_T + logf(g_sumexp[i]);
    const int c = g_cnt[i];
    t1 += (c == 0) ? 1.f : 0.f;
    t5 += (c < 5) ? 1.f : 0.f;
    mr += (float)c;
  }
  #pragma unroll
  for (int o = 32; o >= 1; o >>= 1) {
    nll += __shfl_xor(nll, o, 64);
    t1  += __shfl_xor(t1, o, 64);
    t5  += __shfl_xor(t5, o, 64);
    mr  += __shfl_xor(mr, o, 64);
  }
  __shared__ float red[16][4];
  const int wv = tid >> 6, lane = tid & 63;
  if (lane == 0) { red[wv][0] = nll; red[wv][1] = t1; red[wv][2] = t5; red[wv][3] = mr; }
  __syncthreads();
  if (tid == 0) {
    float a = 0.f, b = 0.f, c = 0.f, d = 0.f;
    for (int k = 0; k < 16; ++k) { a += red[k][0]; b += red[k][1]; c += red[k][2]; d += red[k][3]; }
    out[0] = a / (float)NTOT;
    out[1] = b / (float)NTOT;
    out[2] = c / (float)NTOT;
    out[3] = 1.f + d / (float)NTOT;
  }
}

extern "C" void kernel_launch(void* const* d_in, const int* in_sizes, int n_in,
                              void* d_out, int out_size, void* d_ws, size_t ws_size,
                              hipStream_t stream) {
  const float* f1 = (const float*)d_in[0];
  const float* f2 = (const float*)d_in[1];
  float* out = (float*)d_out;

  knorm<<<dim3(2048), dim3(256), 0, stream>>>(f1, f2);
  kmain<<<dim3(NBLK), dim3(512), 0, stream>>>();
  kfin <<<dim3(1),    dim3(1024), 0, stream>>>(out);
}

// Round 3
// 157.374 us; speedup vs baseline: 1.3896x; 1.3896x over previous
//
#include <hip/hip_runtime.h>
#include <math.h>
#include <stdint.h>

#define NTOT   8192
#define HALF_N 4096
#define DIM    512
#define INV_T  14.2857142857142857f   // 1/0.07
#define NTILE  64                     // 8192 / 128
#define NBLK   2080                   // 64*65/2 triangular; 2080 % 8 == 0 -> bijective XCD swizzle

using s16x8 = __attribute__((ext_vector_type(8))) short;
using f32x4 = __attribute__((ext_vector_type(4))) float;

// Scratch in static device globals (fully rewritten every call; no d_ws use).
__device__ unsigned short g_fnb[NTOT * DIM];   // normalized bf16 matrix, 8 MB
__device__ float g_pos[NTOT];
__device__ float g_ps[NTILE * NTOT];           // per-slot sumexp partials, 2 MB
__device__ int   g_pc[NTILE * NTOT];           // per-slot count partials, 2 MB
__device__ float g_sumexp[NTOT];
__device__ int   g_cnt[NTOT];

__device__ __forceinline__ float bf2f(unsigned short u) {
  union { unsigned int i; float f; } v; v.i = ((unsigned int)u) << 16; return v.f;
}
__device__ __forceinline__ unsigned short f2bf(float x) {
  union { float f; unsigned int i; } v; v.f = x;
  unsigned int u = v.i;
  return (unsigned short)((u + 0x7FFFu + ((u >> 16) & 1u)) >> 16);
}

// async global->LDS, 16 B per lane. LDS dest is wave-uniform base + lane*16.
__device__ __forceinline__ void gload16(const unsigned short* g, unsigned short* l) {
  __builtin_amdgcn_global_load_lds(
      (const __attribute__((address_space(1))) unsigned int*)g,
      (__attribute__((address_space(3))) unsigned int*)l, 16, 0, 0);
}

// ---------------- kernel 1: normalize pairs -> bf16, pos ----------------
__global__ __launch_bounds__(256) void knorm(const float* __restrict__ f1,
                                             const float* __restrict__ f2) {
  const int tid  = threadIdx.x;
  const int wv   = tid >> 6;
  const int pi   = wv >> 1;            // pair within block
  const int half = wv & 1;             // 0: f1 row, 1: f2 row
  const int lane = tid & 63;
  const int b    = blockIdx.x * 2 + pi;
  const int row  = b + half * HALF_N;

  const float* src = (half == 0) ? (f1 + (size_t)b * DIM) : (f2 + (size_t)b * DIM);
  float4 v0 = ((const float4*)src)[lane];
  float4 v1 = ((const float4*)src)[lane + 64];
  float ss = v0.x*v0.x + v0.y*v0.y + v0.z*v0.z + v0.w*v0.w
           + v1.x*v1.x + v1.y*v1.y + v1.z*v1.z + v1.w*v1.w;
  #pragma unroll
  for (int o = 32; o >= 1; o >>= 1) ss += __shfl_xor(ss, o, 64);
  const float sc = 1.0f / fmaxf(sqrtf(ss), 1e-8f);
  ushort4 h0, h1;
  h0.x = f2bf(v0.x * sc); h0.y = f2bf(v0.y * sc);
  h0.z = f2bf(v0.z * sc); h0.w = f2bf(v0.w * sc);
  h1.x = f2bf(v1.x * sc); h1.y = f2bf(v1.y * sc);
  h1.z = f2bf(v1.z * sc); h1.w = f2bf(v1.w * sc);
  ushort4* dst = (ushort4*)(g_fnb + (size_t)row * DIM);
  dst[lane]      = h0;
  dst[lane + 64] = h1;

  // pos[b] = <fn_b, fn_{b+4096}> on the same bf16 values the GEMM uses
  __shared__ ushort4 sh[2][64][2];
  if (half == 1) { sh[pi][lane][0] = h0; sh[pi][lane][1] = h1; }
  __syncthreads();
  if (half == 0) {
    const ushort4 p0 = sh[pi][lane][0], p1 = sh[pi][lane][1];
    float s = bf2f(h0.x)*bf2f(p0.x) + bf2f(h0.y)*bf2f(p0.y)
            + bf2f(h0.z)*bf2f(p0.z) + bf2f(h0.w)*bf2f(p0.w)
            + bf2f(h1.x)*bf2f(p1.x) + bf2f(h1.y)*bf2f(p1.y)
            + bf2f(h1.z)*bf2f(p1.z) + bf2f(h1.w)*bf2f(p1.w);
    #pragma unroll
    for (int o = 32; o >= 1; o >>= 1) s += __shfl_xor(s, o, 64);
    if (lane == 0) { g_pos[b] = s; g_pos[b + HALF_N] = s; }
  }
}

// ---------------- kernel 2: symmetric fused GEMM, atomic-free epilogue ----------------
// R3: counters showed R1/R2 were bound by device-scope atomic RMW traffic
// (FETCH+WRITE matched atomic-count x 64B, not the 8 MB matrix). Epilogue now
// combines the 2 contributing waves per row in LDS (deterministic 2-way adds)
// and emits plain coalesced stores into slot arrays g_ps/g_pc[64][8192]:
// slab s gets slots s..63 from row-side of blocks (s,bj) and slots 0..s-1
// from col-side of blocks (bi,s) -- every slot written exactly once, no RMW.
// kmain geometry = R1's best-measured structure: 128^2 tile, single-buffered
// gload_lds staging (m97-family), 4 blocks/CU, + bijective XCD swizzle.
__global__ __launch_bounds__(256, 4) void kmain() {
  __shared__ __align__(16) unsigned short As[128 * 64];
  __shared__ __align__(16) unsigned short Bs[128 * 64];
  __shared__ float sRowS[128]; __shared__ int sRowC[128];
  __shared__ float sColS[128]; __shared__ int sColC[128];

  // bijective XCD swizzle (2080 = 8*260), then triangular decode t -> (bi,bj)
  int t = (blockIdx.x & 7) * (NBLK / 8) + (blockIdx.x >> 3);
  int bi = 0, rem = NTILE;
  while (t >= rem) { t -= rem; --rem; ++bi; }
  const int bj = bi + t;
  const bool offdiag = (bi != bj);
  const int i0 = bi * 128, j0 = bj * 128;

  const int tid  = threadIdx.x;
  const int lane = tid & 63;
  const int w    = tid >> 6;
  const int wr   = (w >> 1) * 64;   // wave row base
  const int wc   = (w & 1) * 64;    // wave col base
  const int lrow = lane & 15;
  const int lq   = lane >> 4;

  // staging: wave w covers tile rows [w*32, w*32+32) in 4 chunks of 8 rows.
  // Linear LDS dest; inverse-XOR-swizzled global source (rule #21).
  const int rsub = lane >> 3;
  const int lcb  = (lane & 7) ^ rsub;
  const unsigned short* Ag = g_fnb + (size_t)(i0 + w * 32 + rsub) * DIM + lcb * 8;
  const unsigned short* Bg = g_fnb + (size_t)(j0 + w * 32 + rsub) * DIM + lcb * 8;
  unsigned short* Al = &As[w * 32 * 64];
  unsigned short* Bl = &Bs[w * 32 * 64];

  f32x4 acc[4][4];
  #pragma unroll
  for (int a = 0; a < 4; ++a)
    #pragma unroll
    for (int bb = 0; bb < 4; ++bb) { acc[a][bb][0]=0.f; acc[a][bb][1]=0.f; acc[a][bb][2]=0.f; acc[a][bb][3]=0.f; }

  const unsigned short* Bls = offdiag ? (const unsigned short*)Bs
                                      : (const unsigned short*)As;

  for (int kt = 0; kt < 8; ++kt) {
    __syncthreads();                       // prev compute done, LDS reusable
    const int kb = kt * 64;
    #pragma unroll
    for (int q = 0; q < 4; ++q) {
      gload16(Ag + (size_t)(q * 8) * DIM + kb, Al + q * 512);
      if (offdiag) gload16(Bg + (size_t)(q * 8) * DIM + kb, Bl + q * 512);
    }
    __syncthreads();                       // vmcnt(0) drains here -> tile kt visible

    #pragma unroll
    for (int kk = 0; kk < 2; ++kk) {
      s16x8 af[4], bf[4];
      #pragma unroll
      for (int mi = 0; mi < 4; ++mi) {
        const int r = wr + mi * 16 + lrow;
        af[mi] = *(const s16x8*)(&As[r * 64 + (((kk * 4 + lq) ^ (lrow & 7)) * 8)]);
      }
      #pragma unroll
      for (int ni = 0; ni < 4; ++ni) {
        const int r = wc + ni * 16 + lrow;
        bf[ni] = *(const s16x8*)(&Bls[r * 64 + (((kk * 4 + lq) ^ (lrow & 7)) * 8)]);
      }
      #pragma unroll
      for (int mi = 0; mi < 4; ++mi)
        #pragma unroll
        for (int ni = 0; ni < 4; ++ni)
          acc[mi][ni] = __builtin_amdgcn_mfma_f32_16x16x32_bf16(af[mi], bf[ni], acc[mi][ni], 0, 0, 0);
    }
  }

  // ---- epilogue: LDS-combine partials, plain stores (no global atomics) ----
  if (tid < 128) { sRowS[tid] = 0.f; sRowC[tid] = 0; sColS[tid] = 0.f; sColC[tid] = 0; }
  __syncthreads();

  // row side (always): 2 waves contribute per row (wc=0 / wc=64)
  #pragma unroll
  for (int mi = 0; mi < 4; ++mi) {
    #pragma unroll
    for (int r = 0; r < 4; ++r) {
      const int ridx = wr + mi * 16 + lq * 4 + r;     // 0..127
      const int i  = i0 + ridx;
      const float pv = g_pos[i];
      float s = 0.f; int c = 0;
      #pragma unroll
      for (int ni = 0; ni < 4; ++ni) {
        const int j = j0 + wc + ni * 16 + lrow;
        const float v = acc[mi][ni][r];
        const float e = __expf(v * INV_T);
        const bool diag = (j == i);
        s += diag ? 0.f : e;
        c += (!diag && (j != (i ^ HALF_N)) && (v > pv)) ? 1 : 0;
      }
      #pragma unroll
      for (int o = 1; o < 16; o <<= 1) {
        s += __shfl_xor(s, o, 64);
        c += __shfl_xor(c, o, 64);
      }
      if (lrow == 0) {
        atomicAdd(&sRowS[ridx], s);
        atomicAdd(&sRowC[ridx], c);
      }
    }
  }

  // col side (off-diagonal only): 2 waves contribute per col (wr=0 / wr=64)
  if (offdiag) {
    #pragma unroll
    for (int ni = 0; ni < 4; ++ni) {
      const int cidx = wc + ni * 16 + lrow;           // 0..127
      const int j  = j0 + cidx;
      const float pj = g_pos[j];
      float s = 0.f; int c = 0;
      #pragma unroll
      for (int mi = 0; mi < 4; ++mi) {
        #pragma unroll
        for (int r = 0; r < 4; ++r) {
          const int i = i0 + wr + mi * 16 + lq * 4 + r;
          const float v = acc[mi][ni][r];
          s += __expf(v * INV_T);
          c += ((i != (j ^ HALF_N)) && (v > pj)) ? 1 : 0;
        }
      }
      s += __shfl_xor(s, 16, 64); s += __shfl_xor(s, 32, 64);
      c += __shfl_xor(c, 16, 64); c += __shfl_xor(c, 32, 64);
      if (lq == 0) {
        atomicAdd(&sColS[cidx], s);
        atomicAdd(&sColC[cidx], c);
      }
    }
  }
  __syncthreads();

  // slot stores: row side -> slab bi slot bj; col side -> slab bj slot bi
  if (tid < 128) {
    g_ps[(size_t)bj * NTOT + i0 + tid] = sRowS[tid];
    g_pc[(size_t)bj * NTOT + i0 + tid] = sRowC[tid];
  } else if (offdiag && tid < 256) {
    const int r2 = tid - 128;
    g_ps[(size_t)bi * NTOT + j0 + r2] = sColS[r2];
    g_pc[(size_t)bi * NTOT + j0 + r2] = sColC[r2];
  }
}

// ---------------- kernel 2b: fold 64 slots per row ----------------
__global__ __launch_bounds__(256) void kred() {
  const int i = blockIdx.x * 256 + threadIdx.x;
  float s = 0.f; int c = 0;
  #pragma unroll 8
  for (int sl = 0; sl < NTILE; ++sl) {
    s += g_ps[(size_t)sl * NTOT + i];
    c += g_pc[(size_t)sl * NTOT + i];
  }
  g_sumexp[i] = s;
  g_cnt[i] = c;
}

// ---------------- kernel 3: finalize the 4 scalars ----------------
__global__ __launch_bounds__(1024) void kfin(float* __restrict__ out) {
  const int tid = threadIdx.x;
  float nll = 0.f, t1 = 0.f, t5 = 0.f, mr = 0.f;
  for (int i = tid; i < NTOT; i += 1024) {
    nll += -g_pos[i] * INV_T + logf(g_sumexp[i]);
    const int c = g_cnt[i];
    t1 += (c == 0) ? 1.f : 0.f;
    t5 += (c < 5) ? 1.f : 0.f;
    mr += (float)c;
  }
  #pragma unroll
  for (int o = 32; o >= 1; o >>= 1) {
    nll += __shfl_xor(nll, o, 64);
    t1  += __shfl_xor(t1, o, 64);
    t5  += __shfl_xor(t5, o, 64);
    mr  += __shfl_xor(mr, o, 64);
  }
  __shared__ float red[16][4];
  const int wv = tid >> 6, lane = tid & 63;
  if (lane == 0) { red[wv][0] = nll; red[wv][1] = t1; red[wv][2] = t5; red[wv][3] = mr; }
  __syncthreads();
  if (tid == 0) {
    float a = 0.f, b = 0.f, c = 0.f, d = 0.f;
    for (int k = 0; k < 16; ++k) { a += red[k][0]; b += red[k][1]; c += red[k][2]; d += red[k][3]; }
    out[0] = a / (float)NTOT;
    out[1] = b / (float)NTOT;
    out[2] = c / (float)NTOT;
    out[3] = 1.f + d / (float)NTOT;
  }
}

extern "C" void kernel_launch(void* const* d_in, const int* in_sizes, int n_in,
                              void* d_out, int out_size, void* d_ws, size_t ws_size,
                              hipStream_t stream) {
  const float* f1 = (const float*)d_in[0];
  const float* f2 = (const float*)d_in[1];
  float* out = (float*)d_out;

  knorm<<<dim3(2048), dim3(256), 0, stream>>>(f1, f2);
  kmain<<<dim3(NBLK), dim3(256), 0, stream>>>();
  kred <<<dim3(32),   dim3(256), 0, stream>>>();
  kfin <<<dim3(1),    dim3(1024), 0, stream>>>(out);
}